// Round 2
// 258.370 us; speedup vs baseline: 1.0224x; 1.0224x over previous
//
#include <hip/hip_runtime.h>
#include <stdint.h>

typedef unsigned short u16;
typedef __attribute__((ext_vector_type(4))) short short4v;
typedef __attribute__((ext_vector_type(8))) short short8;
typedef __attribute__((ext_vector_type(4))) float floatx4;
typedef __attribute__((ext_vector_type(4))) unsigned short u16x4;

typedef __attribute__((address_space(1))) const void* gas_ptr;
typedef __attribute__((address_space(3))) void* las_ptr;

__device__ __forceinline__ void async16(const void* g, void* l) {
    __builtin_amdgcn_global_load_lds((gas_ptr)g, (las_ptr)l, 16, 0, 0);
}

__device__ __forceinline__ u16 f2bf(float f) {
    union { float f; unsigned int u; } v; v.f = f;
    unsigned int r = v.u + 0x7fffu + ((v.u >> 16) & 1u);
    return (u16)(r >> 16);
}

__device__ __forceinline__ int pk_bf16(float a, float b) {
    return (int)((unsigned int)f2bf(a) | ((unsigned int)f2bf(b) << 16));
}

// fast pack via v_perm: high halves of (a+rnd),(b+rnd); b in high 16
// (verified in baseline; v_cvt_pk_bf16_f32 asm replacement FAILED numerics r1)
__device__ __forceinline__ int pk2(float a, float b) {
    union { float f; unsigned int u; } ua, ub;
    ua.f = a; ub.f = b;
    return (int)__builtin_amdgcn_perm(ub.u + 0x8000u, ua.u + 0x8000u, 0x07060302u);
}

// ---------------- converts ----------------
__global__ void cvt_w_kernel(const float* __restrict__ src, u16* __restrict__ dst) {
    int i = blockIdx.x * 256 + threadIdx.x;
    float4 f = reinterpret_cast<const float4*>(src)[i];
    u16x4 o;
    o.x = f2bf(f.x); o.y = f2bf(f.y); o.z = f2bf(f.z); o.w = f2bf(f.w);
    reinterpret_cast<u16x4*>(dst)[i] = o;
}

__global__ void cvt_x_kernel(const float* __restrict__ x, u16* __restrict__ xb,
                             u16* __restrict__ xout) {
    int i = blockIdx.x * 256 + threadIdx.x;
    float4 f = reinterpret_cast<const float4*>(x)[i];
    u16x4 o;
    o.x = f2bf(f.x); o.y = f2bf(f.y); o.z = f2bf(f.z); o.w = f2bf(f.w);
    reinterpret_cast<u16x4*>(xb)[i] = o;
    int m = (i * 4) >> 10;
    if ((m & 2047) < 256) reinterpret_cast<u16x4*>(xout)[i] = o;
}

// ---------------- NT GEMM: C[m][n] = sum_k A[m][k] * B[n][k] ----------------
// MODE 0: -> Q (pre-scaled by 0.125*log2e) [bh][n][64], K [bh][n][64],
//            Vf lane-tiled for K=32 PV:
//            Vf[bh][key>>5][d>>4][lane = ((key>>3)&3)*16 + (d&15)][key&7]
// MODE 1: -> fp32 out + bias
template<int MODE>
__global__ void __launch_bounds__(256, 2)
gemm_nt(const u16* __restrict__ A, const u16* __restrict__ B,
        u16* __restrict__ q_out, u16* __restrict__ k_out, u16* __restrict__ vt_out,
        float* __restrict__ f_out, const float* __restrict__ bias, int K) {
    __shared__ u16 As[128 * 32];
    __shared__ u16 Bs[128 * 32];
    const int tid  = threadIdx.x;
    const int lane = tid & 63;
    const int w    = tid >> 6;
    const int row0 = blockIdx.x * 128;
    const int col0 = blockIdx.y * 128;
    const int wm   = (w >> 1) * 64;
    const int wn   = (w & 1) * 64;

    floatx4 acc[4][4] = {};

    for (int k0 = 0; k0 < K; k0 += 32) {
        __syncthreads();
#pragma unroll
        for (int i = 0; i < 2; ++i) {
            int pb = w * 128 + i * 64;
            int p  = pb + lane;
            int r  = p >> 2;
            int c  = (p & 3) ^ ((r >> 1) & 3);
            async16(A + (size_t)(row0 + r) * K + (k0 + c * 8), (char*)As + pb * 16);
            async16(B + (size_t)(col0 + r) * K + (k0 + c * 8), (char*)Bs + pb * 16);
        }
        __syncthreads();

        short8 af[4], bf_[4];
#pragma unroll
        for (int t = 0; t < 4; ++t) {
            int ar = wm + t * 16 + (lane & 15);
            int ca = (lane >> 4) ^ ((ar >> 1) & 3);
            af[t]  = *(const short8*)(As + ar * 32 + ca * 8);
            int br = wn + t * 16 + (lane & 15);
            int cb = (lane >> 4) ^ ((br >> 1) & 3);
            bf_[t] = *(const short8*)(Bs + br * 32 + cb * 8);
        }
#pragma unroll
        for (int i = 0; i < 4; ++i)
#pragma unroll
            for (int j = 0; j < 4; ++j)
                acc[i][j] = __builtin_amdgcn_mfma_f32_16x16x32_bf16(af[i], bf_[j], acc[i][j], 0, 0, 0);
    }

#pragma unroll
    for (int i = 0; i < 4; ++i) {
#pragma unroll
        for (int j = 0; j < 4; ++j) {
            int gr0 = row0 + wm + i * 16 + ((lane >> 4) << 2);
            int gc  = col0 + wn + j * 16 + (lane & 15);
            if (MODE == 0) {
                int which = gc >> 10;
                int cl = gc & 1023;
                int h = cl >> 6, d = cl & 63;
                int b = gr0 >> 11, n0 = gr0 & 2047;
                int bh = b * 16 + h;
                if (which == 2) {
                    // keys n0..n0+3 live in one 8-key group: j = (n0&4)+r
                    u16x4 pk;
                    pk.x = f2bf(acc[i][j][0]); pk.y = f2bf(acc[i][j][1]);
                    pk.z = f2bf(acc[i][j][2]); pk.w = f2bf(acc[i][j][3]);
                    size_t off = (size_t)bh * 131072
                               + (((size_t)(n0 >> 5) * 4 + (d >> 4)) * 64
                                  + ((n0 >> 3) & 3) * 16 + (d & 15)) * 8 + (n0 & 4);
                    *reinterpret_cast<u16x4*>(vt_out + off) = pk;
                } else {
                    u16* dst = (which == 0) ? q_out : k_out;
                    float sc = (which == 0) ? 0.18033688f : 1.0f;  // 0.125*log2(e)
#pragma unroll
                    for (int r = 0; r < 4; ++r)
                        dst[((size_t)bh * 2048 + n0 + r) * 64 + d] = f2bf(acc[i][j][r] * sc);
                }
            } else {
                float bv = bias[gc];
#pragma unroll
                for (int r = 0; r < 4; ++r)
                    f_out[(size_t)(gr0 + r) * 1024 + gc] = acc[i][j][r] + bv;
            }
        }
    }
}

// ---------------- flash attention: 32 queries/wave, fixed-max softmax -------
// 1-D grid 896: bh = id&63 (XCD-local K/V), qt = id>>6 (14 tiles of 128 q).
// block 256 = 4 waves; wave owns 32 queries as two 16-query B-frag sets that
// SHARE the K ds_reads and V loads (2x MFMA per staged byte, 2x ILP).
// QK A-operand rows key-permuted so S^T regs land in 16x16x32 B-frag layout;
// PV at K=32 straight from registers.
// lsum on the MFMA pipe: ones-row x P^T B-frag sums all 32 keys of a block
// per call (every lane's acc = full row sum for query lane&15), removing
// 32 VALU adds/kt and the end shfl reduce. Layout-independent: colsum of B
// needs only C/D col = lane&15 (baseline-verified).
__global__ void __launch_bounds__(256, 3)
flash_attn(const u16* __restrict__ Qg, const u16* __restrict__ Kg,
           const u16* __restrict__ Vf, u16* __restrict__ xout) {
    __shared__ u16 Ks[2][64 * 64];
    const int lane = threadIdx.x & 63;
    const int w    = threadIdx.x >> 6;
    const int bh   = blockIdx.x & 63;
    const int qt   = blockIdx.x >> 6;
    const int q0   = 256 + qt * 128 + w * 32;
    const size_t kvbase = (size_t)bh * 2048 * 64;

    const int m = lane & 15;
    const int g = lane >> 4;

    // Q frags (B-operand of 16x16x32): query q0+qs*16+m, k=g*8+j
    short8 qf[2][2];
#pragma unroll
    for (int qs = 0; qs < 2; ++qs) {
        const u16* p = Qg + kvbase + (size_t)(q0 + qs * 16 + m) * 64 + g * 8;
        qf[qs][0] = *(const short8*)(p);
        qf[qs][1] = *(const short8*)(p + 32);
    }

    // V base: frag for (blk32,i) at vp + (blk32*4+i)*512
    const u16* vp = Vf + (size_t)bh * 131072 + lane * 8;

    // K staging: slot p holds row r=p>>3, chunk-pos p&7 = data chunk ^ f(r),
    // f(r) = ((r>>3)&1)*4 + (r&3)
    const int p0 = w * 64 + lane;
#define STAGE_K(buf, kt)                                                        \
    {                                                                           \
        _Pragma("unroll")                                                       \
        for (int i = 0; i < 2; ++i) {                                           \
            int p = i * 256 + p0;                                               \
            int r = p >> 3;                                                     \
            int c = (p & 7) ^ ((((r >> 3) & 1) << 2) | (r & 3));                \
            async16(Kg + kvbase + (size_t)((kt) * 64 + r) * 64 + c * 8,         \
                    (char*)&Ks[buf][0] + p * 16);                               \
        }                                                                       \
    }

    STAGE_K(0, 0);

    // hoisted constants: QK acc init quad (MFMA C-operand, read-only) and
    // all-ones bf16 A-frag for the lsum MFMA
    const floatx4 ZROW = {-32.f, -32.f, -32.f, -32.f};
    short8 ones1;
#pragma unroll
    for (int i = 0; i < 8; ++i) ones1[i] = (short)0x3F80;

    floatx4 lacc[2] = {};
    floatx4 o[2][4] = {};

    const int fm = ((m >> 2) & 1) * 4 + (m & 3);   // = f(r) for this lane's rows

    for (int kt = 0; kt < 32; ++kt) {
        __syncthreads();
        if (kt + 1 < 32) STAGE_K((kt + 1) & 1, kt + 1);

        const u16* kbuf = &Ks[kt & 1][0];
#pragma unroll
        for (int b32 = 0; b32 < 2; ++b32) {
            // V A-frags for this 32-key block (coalesced 16B/lane)
            short8 vfr[4];
#pragma unroll
            for (int i = 0; i < 4; ++i)
                vfr[i] = *(const short8*)(vp + (size_t)((kt * 2 + b32) * 4 + i) * 512);

            // S^T tiles: A row = key b32*32 + (m>>2)*8 + t*4 + (m&3)
            floatx4 sT[2][2];
#pragma unroll
            for (int t = 0; t < 2; ++t) {
                int r = b32 * 32 + (m >> 2) * 8 + t * 4 + (m & 3);
                short8 k0 = *(const short8*)(kbuf + r * 64 + ((g)     ^ fm) * 8);
                short8 k1 = *(const short8*)(kbuf + r * 64 + ((4 + g) ^ fm) * 8);
#pragma unroll
                for (int qs = 0; qs < 2; ++qs) {
                    floatx4 z = __builtin_amdgcn_mfma_f32_16x16x32_bf16(k0, qf[qs][0], ZROW, 0, 0, 0);
                    sT[qs][t] = __builtin_amdgcn_mfma_f32_16x16x32_bf16(k1, qf[qs][1], z, 0, 0, 0);
                }
            }

            // exp2, pack P^T (16x16x32 B-frag: j -> key g*8+j), PV at K=32
#pragma unroll
            for (int qs = 0; qs < 2; ++qs) {
                float p[8];
#pragma unroll
                for (int t = 0; t < 2; ++t)
#pragma unroll
                    for (int r = 0; r < 4; ++r)
                        p[t * 4 + r] = __builtin_amdgcn_exp2f(sT[qs][t][r]);
                union { int i4[4]; short8 s8; } u;
                u.i4[0] = pk2(p[0], p[1]);
                u.i4[1] = pk2(p[2], p[3]);
                u.i4[2] = pk2(p[4], p[5]);
                u.i4[3] = pk2(p[6], p[7]);
#pragma unroll
                for (int i = 0; i < 4; ++i)
                    o[qs][i] = __builtin_amdgcn_mfma_f32_16x16x32_bf16(vfr[i], u.s8, o[qs][i], 0, 0, 0);
                // row-sum of P via ones-MFMA: lacc[qs][*] = sum_k P[q][k]
                lacc[qs] = __builtin_amdgcn_mfma_f32_16x16x32_bf16(ones1, u.s8, lacc[qs], 0, 0, 0);
            }
        }
    }

    const int b = bh >> 4, h = bh & 15;
#pragma unroll
    for (int qs = 0; qs < 2; ++qs) {
        // every lane already holds the full row sum for its query (col=lane&15)
        const float inv = 1.f / lacc[qs][0];

        // epilogue: O^T C-layout: col=q=m, row=d=i*16+g*4+r
        const int n = q0 + qs * 16 + m;
        u16* dst = xout + (size_t)(b * 2048 + n) * 1024 + h * 64 + (g << 2);
#pragma unroll
        for (int i = 0; i < 4; ++i) {
            union { int i2[2]; u16x4 s4; } u;
            u.i2[0] = pk_bf16(o[qs][i][0] * inv, o[qs][i][1] * inv);
            u.i2[1] = pk_bf16(o[qs][i][2] * inv, o[qs][i][3] * inv);
            *reinterpret_cast<u16x4*>(dst + i * 16) = u.s4;
        }
    }
#undef STAGE_K
}

// ---------------- launch ----------------
extern "C" void kernel_launch(void* const* d_in, const int* in_sizes, int n_in,
                              void* d_out, int out_size, void* d_ws, size_t ws_size,
                              hipStream_t stream) {
    const float* x      = (const float*)d_in[0];
    const float* qkv_w  = (const float*)d_in[1];
    const float* proj_w = (const float*)d_in[2];
    const float* proj_b = (const float*)d_in[3];

    char* ws = (char*)d_ws;
    u16* xb    = (u16*)(ws);                       // 16 MB
    u16* xout  = (u16*)(ws + ((size_t)16 << 20));  // 16 MB
    u16* wqkv  = (u16*)(ws + ((size_t)32 << 20));  //  6 MB
    u16* wproj = (u16*)(ws + ((size_t)38 << 20));  //  2 MB
    u16* Qb    = (u16*)(ws + ((size_t)40 << 20));  // 16 MB [bh][n][64] (pre-scaled)
    u16* Kb    = (u16*)(ws + ((size_t)56 << 20));  // 16 MB [bh][n][64]
    u16* Vfb   = (u16*)(ws + ((size_t)72 << 20));  // 16 MB lane-tiled for K=32 PV

    cvt_x_kernel<<<8192, 256, 0, stream>>>(x, xb, xout);
    cvt_w_kernel<<<3072, 256, 0, stream>>>(qkv_w, wqkv);
    cvt_w_kernel<<<1024, 256, 0, stream>>>(proj_w, wproj);
    gemm_nt<0><<<dim3(64, 24), 256, 0, stream>>>(xb, wqkv, Qb, Kb, Vfb, nullptr, nullptr, 1024);
    flash_attn<<<896, 256, 0, stream>>>(Qb, Kb, Vfb, xout);
    gemm_nt<1><<<dim3(64, 8), 256, 0, stream>>>(xout, wproj, nullptr, nullptr, nullptr,
                                                (float*)d_out, proj_b, 1024);
}

// Round 3
// 250.372 us; speedup vs baseline: 1.0551x; 1.0319x over previous
//
#include <hip/hip_runtime.h>
#include <stdint.h>

typedef unsigned short u16;
typedef __attribute__((ext_vector_type(4))) short short4v;
typedef __attribute__((ext_vector_type(8))) short short8;
typedef __attribute__((ext_vector_type(4))) float floatx4;
typedef __attribute__((ext_vector_type(4))) unsigned short u16x4;

typedef __attribute__((address_space(1))) const void* gas_ptr;
typedef __attribute__((address_space(3))) void* las_ptr;

__device__ __forceinline__ void async16(const void* g, void* l) {
    __builtin_amdgcn_global_load_lds((gas_ptr)g, (las_ptr)l, 16, 0, 0);
}

__device__ __forceinline__ u16 f2bf(float f) {
    union { float f; unsigned int u; } v; v.f = f;
    unsigned int r = v.u + 0x7fffu + ((v.u >> 16) & 1u);
    return (u16)(r >> 16);
}

__device__ __forceinline__ int pk_bf16(float a, float b) {
    return (int)((unsigned int)f2bf(a) | ((unsigned int)f2bf(b) << 16));
}

// truncation pack: high halves of {b,a}, b in high 16. P feeds BOTH the PV
// numerator and the ones-MFMA denominator, so the truncation bias is
// common-mode and cancels in the softmax ratio. 1 VALU op vs 3.
// (v_cvt_pk_bf16_f32 asm FAILED numerics in r1 — do not reintroduce.)
__device__ __forceinline__ int pk2t(float a, float b) {
    union { float f; unsigned int u; } ua, ub;
    ua.f = a; ub.f = b;
    return (int)__builtin_amdgcn_perm(ub.u, ua.u, 0x07060302u);
}

// ---------------- converts ----------------
__global__ void cvt_w_kernel(const float* __restrict__ src, u16* __restrict__ dst) {
    int i = blockIdx.x * 256 + threadIdx.x;
    float4 f = reinterpret_cast<const float4*>(src)[i];
    u16x4 o;
    o.x = f2bf(f.x); o.y = f2bf(f.y); o.z = f2bf(f.z); o.w = f2bf(f.w);
    reinterpret_cast<u16x4*>(dst)[i] = o;
}

__global__ void cvt_x_kernel(const float* __restrict__ x, u16* __restrict__ xb,
                             u16* __restrict__ xout) {
    int i = blockIdx.x * 256 + threadIdx.x;
    float4 f = reinterpret_cast<const float4*>(x)[i];
    u16x4 o;
    o.x = f2bf(f.x); o.y = f2bf(f.y); o.z = f2bf(f.z); o.w = f2bf(f.w);
    reinterpret_cast<u16x4*>(xb)[i] = o;
    int m = (i * 4) >> 10;
    if ((m & 2047) < 256) reinterpret_cast<u16x4*>(xout)[i] = o;
}

// ---------------- NT GEMM: C[m][n] = sum_k A[m][k] * B[n][k] ----------------
// MODE 0: -> Q (pre-scaled by 0.125*log2e) [bh][n][64], K [bh][n][64],
//            Vf lane-tiled for K=32 PV:
//            Vf[bh][key>>5][d>>4][lane = ((key>>3)&3)*16 + (d&15)][key&7]
// MODE 1: -> fp32 out + bias
template<int MODE>
__global__ void __launch_bounds__(256, 2)
gemm_nt(const u16* __restrict__ A, const u16* __restrict__ B,
        u16* __restrict__ q_out, u16* __restrict__ k_out, u16* __restrict__ vt_out,
        float* __restrict__ f_out, const float* __restrict__ bias, int K) {
    __shared__ u16 As[128 * 32];
    __shared__ u16 Bs[128 * 32];
    const int tid  = threadIdx.x;
    const int lane = tid & 63;
    const int w    = tid >> 6;
    const int row0 = blockIdx.x * 128;
    const int col0 = blockIdx.y * 128;
    const int wm   = (w >> 1) * 64;
    const int wn   = (w & 1) * 64;

    floatx4 acc[4][4] = {};

    for (int k0 = 0; k0 < K; k0 += 32) {
        __syncthreads();
#pragma unroll
        for (int i = 0; i < 2; ++i) {
            int pb = w * 128 + i * 64;
            int p  = pb + lane;
            int r  = p >> 2;
            int c  = (p & 3) ^ ((r >> 1) & 3);
            async16(A + (size_t)(row0 + r) * K + (k0 + c * 8), (char*)As + pb * 16);
            async16(B + (size_t)(col0 + r) * K + (k0 + c * 8), (char*)Bs + pb * 16);
        }
        __syncthreads();

        short8 af[4], bf_[4];
#pragma unroll
        for (int t = 0; t < 4; ++t) {
            int ar = wm + t * 16 + (lane & 15);
            int ca = (lane >> 4) ^ ((ar >> 1) & 3);
            af[t]  = *(const short8*)(As + ar * 32 + ca * 8);
            int br = wn + t * 16 + (lane & 15);
            int cb = (lane >> 4) ^ ((br >> 1) & 3);
            bf_[t] = *(const short8*)(Bs + br * 32 + cb * 8);
        }
#pragma unroll
        for (int i = 0; i < 4; ++i)
#pragma unroll
            for (int j = 0; j < 4; ++j)
                acc[i][j] = __builtin_amdgcn_mfma_f32_16x16x32_bf16(af[i], bf_[j], acc[i][j], 0, 0, 0);
    }

#pragma unroll
    for (int i = 0; i < 4; ++i) {
#pragma unroll
        for (int j = 0; j < 4; ++j) {
            int gr0 = row0 + wm + i * 16 + ((lane >> 4) << 2);
            int gc  = col0 + wn + j * 16 + (lane & 15);
            if (MODE == 0) {
                int which = gc >> 10;
                int cl = gc & 1023;
                int h = cl >> 6, d = cl & 63;
                int b = gr0 >> 11, n0 = gr0 & 2047;
                int bh = b * 16 + h;
                if (which == 2) {
                    // keys n0..n0+3 live in one 8-key group: j = (n0&4)+r
                    u16x4 pk;
                    pk.x = f2bf(acc[i][j][0]); pk.y = f2bf(acc[i][j][1]);
                    pk.z = f2bf(acc[i][j][2]); pk.w = f2bf(acc[i][j][3]);
                    size_t off = (size_t)bh * 131072
                               + (((size_t)(n0 >> 5) * 4 + (d >> 4)) * 64
                                  + ((n0 >> 3) & 3) * 16 + (d & 15)) * 8 + (n0 & 4);
                    *reinterpret_cast<u16x4*>(vt_out + off) = pk;
                } else {
                    u16* dst = (which == 0) ? q_out : k_out;
                    float sc = (which == 0) ? 0.18033688f : 1.0f;  // 0.125*log2(e)
#pragma unroll
                    for (int r = 0; r < 4; ++r)
                        dst[((size_t)bh * 2048 + n0 + r) * 64 + d] = f2bf(acc[i][j][r] * sc);
                }
            } else {
                float bv = bias[gc];
#pragma unroll
                for (int r = 0; r < 4; ++r)
                    f_out[(size_t)(gr0 + r) * 1024 + gc] = acc[i][j][r] + bv;
            }
        }
    }
}

// ---------------- flash attention: 32 queries/wave, fixed-max softmax -------
// 1-D grid 896: bh = id&63 (XCD-local K/V), qt = id>>6 (14 tiles of 128 q).
// block 256 = 4 waves; wave owns 32 queries as two 16-query B-frag sets that
// SHARE the K ds_reads and V loads (2x MFMA per staged byte, 2x ILP).
// QK A-operand rows key-permuted so S^T regs land in 16x16x32 B-frag layout;
// PV at K=32 straight from registers.
// lsum on the MFMA pipe: ones-row x P^T B-frag sums all 32 keys of a block
// per call (every lane's acc = full row sum for query lane&15).
// P pack is pure truncation (bias cancels in the softmax ratio).
// s_setprio(1) brackets MFMA clusters (T5): 3 independent blocks/CU at
// different kt phases give the scheduler something to arbitrate.
__global__ void __launch_bounds__(256, 3)
flash_attn(const u16* __restrict__ Qg, const u16* __restrict__ Kg,
           const u16* __restrict__ Vf, u16* __restrict__ xout) {
    __shared__ u16 Ks[2][64 * 64];
    const int lane = threadIdx.x & 63;
    const int w    = threadIdx.x >> 6;
    const int bh   = blockIdx.x & 63;
    const int qt   = blockIdx.x >> 6;
    const int q0   = 256 + qt * 128 + w * 32;
    const size_t kvbase = (size_t)bh * 2048 * 64;

    const int m = lane & 15;
    const int g = lane >> 4;

    // Q frags (B-operand of 16x16x32): query q0+qs*16+m, k=g*8+j
    short8 qf[2][2];
#pragma unroll
    for (int qs = 0; qs < 2; ++qs) {
        const u16* p = Qg + kvbase + (size_t)(q0 + qs * 16 + m) * 64 + g * 8;
        qf[qs][0] = *(const short8*)(p);
        qf[qs][1] = *(const short8*)(p + 32);
    }

    // V base: frag for (blk32,i) at vp + (blk32*4+i)*512
    const u16* vp = Vf + (size_t)bh * 131072 + lane * 8;

    // K staging: slot p holds row r=p>>3, chunk-pos p&7 = data chunk ^ f(r),
    // f(r) = ((r>>3)&1)*4 + (r&3)
    const int p0 = w * 64 + lane;
#define STAGE_K(buf, kt)                                                        \
    {                                                                           \
        _Pragma("unroll")                                                       \
        for (int i = 0; i < 2; ++i) {                                           \
            int p = i * 256 + p0;                                               \
            int r = p >> 3;                                                     \
            int c = (p & 7) ^ ((((r >> 3) & 1) << 2) | (r & 3));                \
            async16(Kg + kvbase + (size_t)((kt) * 64 + r) * 64 + c * 8,         \
                    (char*)&Ks[buf][0] + p * 16);                               \
        }                                                                       \
    }

    STAGE_K(0, 0);

    // hoisted constants: QK acc init quad (MFMA C-operand, read-only) and
    // all-ones bf16 A-frag for the lsum MFMA
    const floatx4 ZROW = {-32.f, -32.f, -32.f, -32.f};
    short8 ones1;
#pragma unroll
    for (int i = 0; i < 8; ++i) ones1[i] = (short)0x3F80;

    floatx4 lacc[2] = {};
    floatx4 o[2][4] = {};

    const int fm = ((m >> 2) & 1) * 4 + (m & 3);   // = f(r) for this lane's rows

    for (int kt = 0; kt < 32; ++kt) {
        __syncthreads();
        if (kt + 1 < 32) STAGE_K((kt + 1) & 1, kt + 1);

        const u16* kbuf = &Ks[kt & 1][0];
#pragma unroll
        for (int b32 = 0; b32 < 2; ++b32) {
            // V A-frags for this 32-key block (coalesced 16B/lane)
            short8 vfr[4];
#pragma unroll
            for (int i = 0; i < 4; ++i)
                vfr[i] = *(const short8*)(vp + (size_t)((kt * 2 + b32) * 4 + i) * 512);

            // S^T tiles: A row = key b32*32 + (m>>2)*8 + t*4 + (m&3)
            floatx4 sT[2][2];
#pragma unroll
            for (int t = 0; t < 2; ++t) {
                int r = b32 * 32 + (m >> 2) * 8 + t * 4 + (m & 3);
                short8 k0 = *(const short8*)(kbuf + r * 64 + ((g)     ^ fm) * 8);
                short8 k1 = *(const short8*)(kbuf + r * 64 + ((4 + g) ^ fm) * 8);
                __builtin_amdgcn_s_setprio(1);
#pragma unroll
                for (int qs = 0; qs < 2; ++qs) {
                    floatx4 z = __builtin_amdgcn_mfma_f32_16x16x32_bf16(k0, qf[qs][0], ZROW, 0, 0, 0);
                    sT[qs][t] = __builtin_amdgcn_mfma_f32_16x16x32_bf16(k1, qf[qs][1], z, 0, 0, 0);
                }
                __builtin_amdgcn_s_setprio(0);
            }

            // exp2, pack P^T (16x16x32 B-frag: j -> key g*8+j), PV at K=32
#pragma unroll
            for (int qs = 0; qs < 2; ++qs) {
                float p[8];
#pragma unroll
                for (int t = 0; t < 2; ++t)
#pragma unroll
                    for (int r = 0; r < 4; ++r)
                        p[t * 4 + r] = __builtin_amdgcn_exp2f(sT[qs][t][r]);
                union { int i4[4]; short8 s8; } u;
                u.i4[0] = pk2t(p[0], p[1]);
                u.i4[1] = pk2t(p[2], p[3]);
                u.i4[2] = pk2t(p[4], p[5]);
                u.i4[3] = pk2t(p[6], p[7]);
                __builtin_amdgcn_s_setprio(1);
#pragma unroll
                for (int i = 0; i < 4; ++i)
                    o[qs][i] = __builtin_amdgcn_mfma_f32_16x16x32_bf16(vfr[i], u.s8, o[qs][i], 0, 0, 0);
                // row-sum of P via ones-MFMA: lacc[qs][*] = sum_k P[q][k]
                lacc[qs] = __builtin_amdgcn_mfma_f32_16x16x32_bf16(ones1, u.s8, lacc[qs], 0, 0, 0);
                __builtin_amdgcn_s_setprio(0);
            }
        }
    }

    const int b = bh >> 4, h = bh & 15;
#pragma unroll
    for (int qs = 0; qs < 2; ++qs) {
        // every lane already holds the full row sum for its query (col=lane&15)
        const float inv = 1.f / lacc[qs][0];

        // epilogue: O^T C-layout: col=q=m, row=d=i*16+g*4+r
        const int n = q0 + qs * 16 + m;
        u16* dst = xout + (size_t)(b * 2048 + n) * 1024 + h * 64 + (g << 2);
#pragma unroll
        for (int i = 0; i < 4; ++i) {
            union { int i2[2]; u16x4 s4; } u;
            u.i2[0] = pk_bf16(o[qs][i][0] * inv, o[qs][i][1] * inv);
            u.i2[1] = pk_bf16(o[qs][i][2] * inv, o[qs][i][3] * inv);
            *reinterpret_cast<u16x4*>(dst + i * 16) = u.s4;
        }
    }
#undef STAGE_K
}

// ---------------- launch ----------------
extern "C" void kernel_launch(void* const* d_in, const int* in_sizes, int n_in,
                              void* d_out, int out_size, void* d_ws, size_t ws_size,
                              hipStream_t stream) {
    const float* x      = (const float*)d_in[0];
    const float* qkv_w  = (const float*)d_in[1];
    const float* proj_w = (const float*)d_in[2];
    const float* proj_b = (const float*)d_in[3];

    char* ws = (char*)d_ws;
    u16* xb    = (u16*)(ws);                       // 16 MB
    u16* xout  = (u16*)(ws + ((size_t)16 << 20));  // 16 MB
    u16* wqkv  = (u16*)(ws + ((size_t)32 << 20));  //  6 MB
    u16* wproj = (u16*)(ws + ((size_t)38 << 20));  //  2 MB
    u16* Qb    = (u16*)(ws + ((size_t)40 << 20));  // 16 MB [bh][n][64] (pre-scaled)
    u16* Kb    = (u16*)(ws + ((size_t)56 << 20));  // 16 MB [bh][n][64]
    u16* Vfb   = (u16*)(ws + ((size_t)72 << 20));  // 16 MB lane-tiled for K=32 PV

    cvt_x_kernel<<<8192, 256, 0, stream>>>(x, xb, xout);
    cvt_w_kernel<<<3072, 256, 0, stream>>>(qkv_w, wqkv);
    cvt_w_kernel<<<1024, 256, 0, stream>>>(proj_w, wproj);
    gemm_nt<0><<<dim3(64, 24), 256, 0, stream>>>(xb, wqkv, Qb, Kb, Vfb, nullptr, nullptr, 1024);
    flash_attn<<<896, 256, 0, stream>>>(Qb, Kb, Vfb, xout);
    gemm_nt<1><<<dim3(64, 8), 256, 0, stream>>>(xout, wproj, nullptr, nullptr, nullptr,
                                                (float*)d_out, proj_b, 1024);
}